// Round 1
// baseline (19428.551 us; speedup 1.0000x reference)
//
#include <hip/hip_runtime.h>

namespace {

constexpr int E  = 64;
constexpr int H  = 4;
constexpr int HD = 16;
constexpr int FF = 32;
constexpr int NL = 9;
constexpr int S  = 7;
constexpr int B  = 8192;
constexpr int G  = 4;            // sequences per block
constexpr int MQ = G * S;        // 28 query rows per block
constexpr int NT = 256;          // threads per block

// Generic projection: dst(r, c) = bias[c] + sum_k src(r)[k] * W[c][k]
// Thread t: c = t&63 (output column), w = t>>6; rows r = w + 4*i, i < NR.
// W row c (K4*4 floats) is preloaded into registers; state rows are read
// from LDS as float4 broadcasts (all lanes of a wave read the same address).
template <int NR, int K4, class SrcFn, class OutFn>
__device__ __forceinline__ void proj(const float* __restrict__ W,
                                     const float* __restrict__ bias,
                                     int c, int w, SrcFn src, OutFn outfn)
{
    const float* Wc = W + c * (K4 * 4);
    float4 wr[K4];
#pragma unroll
    for (int k4 = 0; k4 < K4; ++k4)
        wr[k4] = *(const float4*)(Wc + 4 * k4);
    const float bc = bias[c];
    float acc[NR];
#pragma unroll
    for (int i = 0; i < NR; ++i) acc[i] = bc;
#pragma unroll
    for (int k4 = 0; k4 < K4; ++k4) {
#pragma unroll
        for (int i = 0; i < NR; ++i) {
            const float* row = src(w + 4 * i);
            float4 a = *(const float4*)(row + 4 * k4);
            acc[i] = fmaf(a.x, wr[k4].x, acc[i]);
            acc[i] = fmaf(a.y, wr[k4].y, acc[i]);
            acc[i] = fmaf(a.z, wr[k4].z, acc[i]);
            acc[i] = fmaf(a.w, wr[k4].w, acc[i]);
        }
    }
#pragma unroll
    for (int i = 0; i < NR; ++i) outfn(w + 4 * i, acc[i]);
}

// One multi-head attention block, updating stQ in place (residual add).
// SKV = kv length per sequence: 7 (self-attn) or 14 (cross-attn over [f1;f2]).
template <int SKV>
__device__ __forceinline__ void mha_block(
    float (*stQ)[E], const float (*kvA)[E], const float (*kvB)[E],
    const float* __restrict__ win,  const float* __restrict__ bin,
    const float* __restrict__ wout, const float* __restrict__ bout,
    float (*qb)[E], float (*kb)[E], float (*vb)[E], float (*cx)[E],
    int t)
{
    const int c = t & 63, w = t >> 6;
    constexpr int NKV = G * SKV / 4;   // rows per thread for k/v proj: 7 or 14

    auto kvsrc = [&](int r) -> const float* {
        if constexpr (SKV == 7) {
            return kvA[r];
        } else {
            int g = r / 14, j = r - g * 14;
            return (j < 7) ? kvA[g * 7 + j] : kvB[g * 7 + (j - 7)];
        }
    };

    // Q projection: rows MQ
    proj<MQ / 4, 16>(win, bin, c, w,
        [&](int r) -> const float* { return stQ[r]; },
        [&](int r, float v) { qb[r][c] = v; });
    // K projection: rows G*SKV
    proj<NKV, 16>(win + 64 * E, bin + 64, c, w, kvsrc,
        [&](int r, float v) { kb[r][c] = v; });
    // V projection
    proj<NKV, 16>(win + 128 * E, bin + 128, c, w, kvsrc,
        [&](int r, float v) { vb[r][c] = v; });

    __syncthreads();

    // Attention: one thread per (g, h, query i) -> 4*4*7 = 112 threads
    if (t < G * H * S) {
        const int gh = t / S, qi = t - gh * S;
        const int g = gh >> 2, h = gh & 3;
        const int qrow = g * S + qi;
        const float* qp = &qb[qrow][h * HD];
        float sc[SKV];
        float mx = -1e30f;
#pragma unroll
        for (int j = 0; j < SKV; ++j) {
            const float* kp = &kb[g * SKV + j][h * HD];
            float s = 0.f;
#pragma unroll
            for (int d = 0; d < HD; ++d) s = fmaf(qp[d], kp[d], s);
            s *= 0.25f;   // 1/sqrt(HD)
            sc[j] = s;
            mx = fmaxf(mx, s);
        }
        float ssum = 0.f;
#pragma unroll
        for (int j = 0; j < SKV; ++j) { sc[j] = __expf(sc[j] - mx); ssum += sc[j]; }
        const float inv = 1.0f / ssum;
        float o[HD];
#pragma unroll
        for (int d = 0; d < HD; ++d) o[d] = 0.f;
#pragma unroll
        for (int j = 0; j < SKV; ++j) {
            const float p = sc[j] * inv;
            const float* vp = &vb[g * SKV + j][h * HD];
#pragma unroll
            for (int d = 0; d < HD; ++d) o[d] = fmaf(p, vp[d], o[d]);
        }
        float* op = &cx[qrow][h * HD];
#pragma unroll
        for (int d = 0; d < HD; ++d) op[d] = o[d];
    }
    __syncthreads();

    // Output projection + residual
    proj<MQ / 4, 16>(wout, bout, c, w,
        [&](int r) -> const float* { return cx[r]; },
        [&](int r, float v) { stQ[r][c] += v; });
    __syncthreads();
}

__device__ __forceinline__ void ffn_block(
    float (*st)[E],
    const float* __restrict__ w1, const float* __restrict__ b1,
    const float* __restrict__ w2, const float* __restrict__ b2,
    float (*hb)[E], int t)
{
    const int c = t & 63, w = t >> 6;
    if (c < FF) {
        proj<MQ / 4, 16>(w1, b1, c, w,
            [&](int r) -> const float* { return st[r]; },
            [&](int r, float v) { hb[r][c] = fmaxf(v, 0.f); });
    }
    __syncthreads();
    proj<MQ / 4, 8>(w2, b2, c, w,      // K = 32
        [&](int r) -> const float* { return hb[r]; },
        [&](int r, float v) { st[r][c] += v; });
    __syncthreads();
}

__global__ __launch_bounds__(NT, 2)
void pose_kernel(
    const float* __restrict__ feature1, const float* __restrict__ feature2,
    const float* __restrict__ sa1_win,  const float* __restrict__ sa1_bin,
    const float* __restrict__ sa1_wout, const float* __restrict__ sa1_bout,
    const float* __restrict__ sa2_win,  const float* __restrict__ sa2_bin,
    const float* __restrict__ sa2_wout, const float* __restrict__ sa2_bout,
    const float* __restrict__ ca_win,   const float* __restrict__ ca_bin,
    const float* __restrict__ ca_wout,  const float* __restrict__ ca_bout,
    const float* __restrict__ ff_w1,    const float* __restrict__ ff_b1,
    const float* __restrict__ ff_w2,    const float* __restrict__ ff_b2,
    const float* __restrict__ query_embed,
    const float* __restrict__ fc_rot_w, const float* __restrict__ fc_rot_b,
    const float* __restrict__ fc_trans_w, const float* __restrict__ fc_trans_b,
    float* __restrict__ out)
{
    __shared__ __align__(16) float sF1[MQ][E];
    __shared__ __align__(16) float sF2[MQ][E];
    __shared__ __align__(16) float sQ [MQ][E];
    __shared__ __align__(16) float qb [MQ][E];
    __shared__ __align__(16) float kb [G * 14][E];
    __shared__ __align__(16) float vb [G * 14][E];
    __shared__ __align__(16) float cx [MQ][E];

    const int t  = threadIdx.x;
    const int bi = blockIdx.y;          // branch: 0 = rot, 1 = trn
    const int b0 = blockIdx.x * G;      // first batch element of this block

    // Load per-sequence state. G consecutive sequences are contiguous:
    // feature1[b0 .. b0+G) is MQ*E contiguous floats -> coalesced.
    {
        const float* f1p = feature1 + (size_t)b0 * S * E;
        const float* f2p = feature2 + (size_t)b0 * S * E;
        const float* qe  = query_embed + (size_t)bi * S * E;
        for (int idx = t; idx < MQ * E; idx += NT) {
            ((float*)sF1)[idx] = f1p[idx];
            ((float*)sF2)[idx] = f2p[idx];
            const int r = idx >> 6;
            const int s = r % S;
            ((float*)sQ)[idx] = qe[s * E + (idx & 63)];
        }
    }
    __syncthreads();

    for (int li = 0; li < NL; ++li) {
        const size_t wo = (size_t)bi * NL + li;
        mha_block<7>(sF1, sF1, nullptr,
                     sa1_win + wo * 192 * E, sa1_bin + wo * 192,
                     sa1_wout + wo * E * E,  sa1_bout + wo * E,
                     qb, kb, vb, cx, t);
        mha_block<7>(sF2, sF2, nullptr,
                     sa2_win + wo * 192 * E, sa2_bin + wo * 192,
                     sa2_wout + wo * E * E,  sa2_bout + wo * E,
                     qb, kb, vb, cx, t);
        mha_block<14>(sQ, sF1, sF2,
                      ca_win + wo * 192 * E, ca_bin + wo * 192,
                      ca_wout + wo * E * E,  ca_bout + wo * E,
                      qb, kb, vb, cx, t);
        ffn_block(sQ, ff_w1 + wo * FF * E, ff_b1 + wo * FF,
                  ff_w2 + wo * E * FF, ff_b2 + wo * E, qb, t);
    }

    // Pose head: out[b] = [rot(4) | trn(3)]; mean over the 7 tokens.
    if (bi == 0) {
        if (t < G * 4) {
            const int g = t >> 2, cc = t & 3;
            const float* wv = fc_rot_w + cc * E;
            float acc = 0.f;
            for (int s = 0; s < S; ++s) {
                const float* qp = sQ[g * S + s];
                for (int k = 0; k < E; ++k) acc = fmaf(qp[k], wv[k], acc);
            }
            out[(size_t)(b0 + g) * 7 + cc] = acc * (1.0f / 7.0f) + fc_rot_b[cc];
        }
    } else {
        if (t < G * 3) {
            const int g = t / 3, cc = t - g * 3;
            const float* wv = fc_trans_w + cc * E;
            float acc = 0.f;
            for (int s = 0; s < S; ++s) {
                const float* qp = sQ[g * S + s];
                for (int k = 0; k < E; ++k) acc = fmaf(qp[k], wv[k], acc);
            }
            out[(size_t)(b0 + g) * 7 + 4 + cc] = acc * (1.0f / 7.0f) + fc_trans_b[cc];
        }
    }
}

} // namespace

extern "C" void kernel_launch(void* const* d_in, const int* in_sizes, int n_in,
                              void* d_out, int out_size, void* d_ws, size_t ws_size,
                              hipStream_t stream)
{
    const float* feature1   = (const float*)d_in[0];
    const float* feature2   = (const float*)d_in[1];
    const float* sa1_win    = (const float*)d_in[2];
    const float* sa1_bin    = (const float*)d_in[3];
    const float* sa1_wout   = (const float*)d_in[4];
    const float* sa1_bout   = (const float*)d_in[5];
    const float* sa2_win    = (const float*)d_in[6];
    const float* sa2_bin    = (const float*)d_in[7];
    const float* sa2_wout   = (const float*)d_in[8];
    const float* sa2_bout   = (const float*)d_in[9];
    const float* ca_win     = (const float*)d_in[10];
    const float* ca_bin     = (const float*)d_in[11];
    const float* ca_wout    = (const float*)d_in[12];
    const float* ca_bout    = (const float*)d_in[13];
    const float* ff_w1      = (const float*)d_in[14];
    const float* ff_b1      = (const float*)d_in[15];
    const float* ff_w2      = (const float*)d_in[16];
    const float* ff_b2      = (const float*)d_in[17];
    const float* query_embed= (const float*)d_in[18];
    const float* fc_rot_w   = (const float*)d_in[19];
    const float* fc_rot_b   = (const float*)d_in[20];
    const float* fc_trans_w = (const float*)d_in[21];
    const float* fc_trans_b = (const float*)d_in[22];

    dim3 grid(B / G, 2);
    pose_kernel<<<grid, NT, 0, stream>>>(
        feature1, feature2,
        sa1_win, sa1_bin, sa1_wout, sa1_bout,
        sa2_win, sa2_bin, sa2_wout, sa2_bout,
        ca_win, ca_bin, ca_wout, ca_bout,
        ff_w1, ff_b1, ff_w2, ff_b2,
        query_embed, fc_rot_w, fc_rot_b, fc_trans_w, fc_trans_b,
        (float*)d_out);
}

// Round 2
// 2933.067 us; speedup vs baseline: 6.6240x; 6.6240x over previous
//
#include <hip/hip_runtime.h>
#include <hip/hip_bf16.h>

namespace {

using bf16x8 = __attribute__((ext_vector_type(8))) short;
using f32x4  = __attribute__((ext_vector_type(4))) float;

constexpr int E = 64, NL = 9, S = 7, BB = 8192;
constexpr int G = 16;            // sequences per block
constexpr int M = G * S;         // 112 rows
constexpr int NTHREADS = 512;

// LDS layout (bytes). fp32 state tiles are [112][64] swizzled (32B granule),
// bf16 tiles [*][64] swizzled (16B granule). vt = V^T bf16 [64][256] swizzled.
constexpr int OFF_F1 = 0;
constexpr int OFF_F2 = 28672;
constexpr int OFF_Q  = 57344;
constexpr int OFF_QB = 86016;    // q / ctx / ffn-hidden bf16 [112][64]
constexpr int OFF_KB = 100352;   // k bf16 [224][64]
constexpr int OFF_PB = 129024;   // per-wave P tiles: 8 waves x 224 B
constexpr int OFF_VT = 130816;   // V^T bf16 [64][256]
constexpr int SMEM_TOTAL = 163584;   // <= 163840

__device__ __forceinline__ short f2bf(float f) {
  union { __hip_bfloat16 h; short s; } u;
  u.h = __float2bfloat16(f);
  return u.s;
}

__device__ __forceinline__ int swzS(int r, int c) {   // fp32 [*][64]
  return r * 256 + ((((c >> 3) ^ (r & 7)) << 5) | ((c & 7) << 2));
}
__device__ __forceinline__ int swzB(int r, int c) {   // bf16 [*][64]
  return r * 128 + ((((c >> 3) ^ (r & 7)) << 4) | ((c & 7) << 1));
}

// 8 consecutive fp32 (c0 % 8 == 0) from swizzled fp32 tile -> bf16x8 fragment
__device__ __forceinline__ bf16x8 ldA_st(const char* base, int r, int c0) {
  const float4* p = (const float4*)(base + r * 256 + (((c0 >> 3) ^ (r & 7)) << 5));
  float4 x = p[0], y = p[1];
  bf16x8 v;
  v[0] = f2bf(x.x); v[1] = f2bf(x.y); v[2] = f2bf(x.z); v[3] = f2bf(x.w);
  v[4] = f2bf(y.x); v[5] = f2bf(y.y); v[6] = f2bf(y.z); v[7] = f2bf(y.w);
  return v;
}
// 8 consecutive bf16 (c0 % 8 == 0) from swizzled bf16 tile
__device__ __forceinline__ bf16x8 ldA_bf(const char* base, int r, int c0) {
  return *(const bf16x8*)(base + r * 128 + (((c0 >> 3) ^ (r & 7)) << 4));
}

// Generic tiled GEMM: OUT[M x N] = A[M x K] * W^T (W is [N][K] row-major) + bias.
// Wave grid: wm = wid>>2 splits M-tiles, wn = wid&3 splits N-tiles.
// A fragments cached in registers per wave; B fragments loaded once per N-tile.
template <int MT, int NTT, int KF, bool WS, class AF, class DF>
__device__ __forceinline__ void gemm(const short* __restrict__ wbf,
                                     const float* __restrict__ wf,
                                     const float* __restrict__ bias,
                                     int ldK, int wid, int mrow, int kgrp,
                                     AF ldA, DF stD)
{
  const int wm = wid >> 2, wn = wid & 3;
  const int mt0 = (MT * wm) >> 1, mt1 = (MT * (wm + 1)) >> 1;
  const int nt0 = (NTT * wn) >> 2, nt1 = (NTT * (wn + 1)) >> 2;
  constexpr int MYMT = (MT + 1) / 2;
  bf16x8 aC[MYMT][KF];
#pragma unroll
  for (int i = 0; i < MYMT; ++i) {
    if (mt0 + i < mt1) {
#pragma unroll
      for (int kf = 0; kf < KF; ++kf)
        aC[i][kf] = ldA((mt0 + i) * 16 + mrow, kf * 32 + kgrp * 8);
    }
  }
  for (int nt = nt0; nt < nt1; ++nt) {
    bf16x8 bC[KF];
#pragma unroll
    for (int kf = 0; kf < KF; ++kf) {
      if constexpr (WS) {
        bC[kf] = *(const bf16x8*)(wbf + (nt * 16 + mrow) * ldK + kf * 32 + kgrp * 8);
      } else {
        const float* wp = wf + (nt * 16 + mrow) * ldK + kf * 32 + kgrp * 8;
        float4 x = *(const float4*)wp, y = *(const float4*)(wp + 4);
        bf16x8 v;
        v[0] = f2bf(x.x); v[1] = f2bf(x.y); v[2] = f2bf(x.z); v[3] = f2bf(x.w);
        v[4] = f2bf(y.x); v[5] = f2bf(y.y); v[6] = f2bf(y.z); v[7] = f2bf(y.w);
        bC[kf] = v;
      }
    }
    const float bv = bias[nt * 16 + mrow];
#pragma unroll
    for (int i = 0; i < MYMT; ++i) {
      if (mt0 + i < mt1) {
        f32x4 acc = { bv, bv, bv, bv };
#pragma unroll
        for (int kf = 0; kf < KF; ++kf)
          acc = __builtin_amdgcn_mfma_f32_16x16x32_bf16(aC[i][kf], bC[kf], acc, 0, 0, 0);
        stD(mt0 + i, nt, acc);
      }
    }
  }
}

// Attention phase. One (seq g, head h) pair per wave-iteration, no cross-wave
// sync needed (each pair's ctx overwrites exactly its own q region of qb).
// kb rows: SA -> 7g+j ; CA -> 14g+j. V^T col base: SA -> 8g ; CA -> 16g.
template <bool CA>
__device__ __forceinline__ void attn_phase(char* qb, char* kbp, char* vt, char* pbw,
                                           int wid, int mrow, int kgrp)
{
  constexpr int KVL = CA ? 14 : 7;
  for (int i = 0; i < 8; ++i) {
    const int pidx = wid * 8 + i;
    const int g = pidx >> 2, h = pidx & 3;
    bf16x8 aq = {}, bk = {};
    if (kgrp < 2) {
      int qr = g * 7 + mrow; qr = qr > 111 ? 111 : qr;
      aq = ldA_bf(qb, qr, h * 16 + kgrp * 8);
      int kr = CA ? (g * 14 + mrow) : (g * 7 + mrow);
      const int krmax = CA ? 223 : 111;
      kr = kr > krmax ? krmax : kr;
      bk = ldA_bf(kbp, kr, h * 16 + kgrp * 8);
    }
    f32x4 s = { 0.f, 0.f, 0.f, 0.f };
    s = __builtin_amdgcn_mfma_f32_16x16x32_bf16(aq, bk, s, 0, 0, 0);
    // softmax over kv (= lane&15 within 16-lane groups); rows = kgrp*4+j
    const bool valid = mrow < KVL;
    float pr[4];
#pragma unroll
    for (int j = 0; j < 4; ++j) {
      float v = valid ? s[j] * 0.25f : -3.0e38f;
      float mx = v;
      mx = fmaxf(mx, __shfl_xor(mx, 1));
      mx = fmaxf(mx, __shfl_xor(mx, 2));
      mx = fmaxf(mx, __shfl_xor(mx, 4));
      mx = fmaxf(mx, __shfl_xor(mx, 8));
      float e = valid ? __expf(v - mx) : 0.f;
      float sm = e;
      sm += __shfl_xor(sm, 1);
      sm += __shfl_xor(sm, 2);
      sm += __shfl_xor(sm, 4);
      sm += __shfl_xor(sm, 8);
      pr[j] = e / sm;
    }
#pragma unroll
    for (int j = 0; j < 4; ++j) {
      int row = kgrp * 4 + j;
      if (row < 7)
        *(short*)(pbw + row * 32 + mrow * 2) = f2bf(pr[j]);
    }
    bf16x8 ap = {}, bv = {};
    if (kgrp < 2) {
      ap = *(const bf16x8*)(pbw + mrow * 32 + kgrp * 16);
      int vr = h * 16 + mrow;
      int cb = (CA ? g * 16 : g * 8) + kgrp * 8;
      bv = *(const bf16x8*)(vt + vr * 512 + (((cb >> 3) ^ (vr & 7)) << 4));
    }
    f32x4 o = { 0.f, 0.f, 0.f, 0.f };
    o = __builtin_amdgcn_mfma_f32_16x16x32_bf16(ap, bv, o, 0, 0, 0);
#pragma unroll
    for (int j = 0; j < 4; ++j) {
      int row = kgrp * 4 + j;
      if (row < 7) {
        int rr = g * 7 + row, cc = h * 16 + mrow;
        *(short*)(qb + swzB(rr, cc)) = f2bf(o[j]);
      }
    }
  }
}

template <bool WS>
__global__ __launch_bounds__(NTHREADS, 2) void pose_kernel(
    const float* __restrict__ feature1, const float* __restrict__ feature2,
    const float* __restrict__ sa1_win, const float* __restrict__ sa1_bin,
    const float* __restrict__ sa1_wout, const float* __restrict__ sa1_bout,
    const float* __restrict__ sa2_win, const float* __restrict__ sa2_bin,
    const float* __restrict__ sa2_wout, const float* __restrict__ sa2_bout,
    const float* __restrict__ ca_win, const float* __restrict__ ca_bin,
    const float* __restrict__ ca_wout, const float* __restrict__ ca_bout,
    const float* __restrict__ ff_w1, const float* __restrict__ ff_b1,
    const float* __restrict__ ff_w2, const float* __restrict__ ff_b2,
    const float* __restrict__ query_embed,
    const float* __restrict__ fc_rot_w, const float* __restrict__ fc_rot_b,
    const float* __restrict__ fc_trans_w, const float* __restrict__ fc_trans_b,
    const short* __restrict__ wbf, float* __restrict__ out)
{
  extern __shared__ char smem[];
  char* sF1 = smem + OFF_F1;
  char* sF2 = smem + OFF_F2;
  char* sQ  = smem + OFF_Q;
  char* qb  = smem + OFF_QB;
  char* kbp = smem + OFF_KB;
  char* vt  = smem + OFF_VT;

  const int t = threadIdx.x;
  const int wid  = t >> 6;
  const int mrow = t & 15;
  const int kgrp = (t >> 4) & 3;
  char* pbw = smem + OFF_PB + wid * 224;
  const int bi = blockIdx.y;
  const int b0 = blockIdx.x * G;

  // ---- load per-sequence state ----
  {
    const float* f1p = feature1 + (size_t)b0 * (S * E);
    const float* f2p = feature2 + (size_t)b0 * (S * E);
    const float* qe  = query_embed + (size_t)bi * (S * E);
    for (int idx = t; idx < M * E; idx += NTHREADS) {
      int r = idx >> 6, c = idx & 63;
      *(float*)(sF1 + swzS(r, c)) = f1p[idx];
      *(float*)(sF2 + swzS(r, c)) = f2p[idx];
      *(float*)(sQ + swzS(r, c))  = qe[(r % 7) * 64 + c];
    }
  }
  __syncthreads();

  for (int li = 0; li < NL; ++li) {
    const int wo = bi * NL + li;
    const short* W_in[3]  = { wbf + 0      + wo * 12288,
                              wbf + 221184 + wo * 12288,
                              wbf + 442368 + wo * 12288 };
    const short* W_out[3] = { wbf + 663552 + wo * 4096,
                              wbf + 737280 + wo * 4096,
                              wbf + 811008 + wo * 4096 };
    const short* W_f1 = wbf + 884736 + wo * 2048;
    const short* W_f2 = wbf + 921600 + wo * 2048;
    const float* F_in[3]  = { sa1_win + wo * 12288, sa2_win + wo * 12288, ca_win + wo * 12288 };
    const float* F_out[3] = { sa1_wout + wo * 4096, sa2_wout + wo * 4096, ca_wout + wo * 4096 };
    const float* B_in[3]  = { sa1_bin + wo * 192, sa2_bin + wo * 192, ca_bin + wo * 192 };
    const float* B_out[3] = { sa1_bout + wo * 64, sa2_bout + wo * 64, ca_bout + wo * 64 };
    const float* F_f1 = ff_w1 + wo * 2048;
    const float* F_f2 = ff_w2 + wo * 2048;
    const float* B_f1 = ff_b1 + wo * 32;
    const float* B_f2 = ff_b2 + wo * 64;

    // ---------- self-attention on f1, then f2 ----------
    for (int sa = 0; sa < 2; ++sa) {
      char* ST = sa ? sF2 : sF1;
      auto ldA = [&](int r, int k0) { return ldA_st(ST, r, k0); };
      auto stQKV = [&](int mt, int nt, f32x4 a) {
        int r0 = mt * 16 + kgrp * 4;
        if (nt < 4) {
          int c = nt * 16 + mrow;
#pragma unroll
          for (int j = 0; j < 4; ++j) *(short*)(qb + swzB(r0 + j, c)) = f2bf(a[j]);
        } else if (nt < 8) {
          int c = (nt - 4) * 16 + mrow;
#pragma unroll
          for (int j = 0; j < 4; ++j) *(short*)(kbp + swzB(r0 + j, c)) = f2bf(a[j]);
        } else {
          int d = (nt - 8) * 16 + mrow;
#pragma unroll
          for (int j = 0; j < 4; ++j) {
            int r = r0 + j;
            int gg = r / 7;
            int col = gg * 8 + (r - gg * 7);
            *(short*)(vt + d * 512 + ((((col >> 3) ^ (d & 7)) << 4) | ((col & 7) << 1))) = f2bf(a[j]);
          }
        }
      };
      gemm<7, 12, 2, WS>(W_in[sa], F_in[sa], B_in[sa], 64, wid, mrow, kgrp, ldA, stQKV);
      __syncthreads();
      attn_phase<false>(qb, kbp, vt, pbw, wid, mrow, kgrp);
      __syncthreads();
      auto ldCtx = [&](int r, int k0) { return ldA_bf(qb, r, k0); };
      auto stRes = [&](int mt, int nt, f32x4 a) {
        int r0 = mt * 16 + kgrp * 4;
        int c = nt * 16 + mrow;
#pragma unroll
        for (int j = 0; j < 4; ++j) {
          float* p = (float*)(ST + swzS(r0 + j, c));
          *p += a[j];
        }
      };
      gemm<7, 4, 2, WS>(W_out[sa], F_out[sa], B_out[sa], 64, wid, mrow, kgrp, ldCtx, stRes);
      __syncthreads();
    }

    // ---------- cross-attention ----------
    {
      auto ldQ = [&](int r, int k0) { return ldA_st(sQ, r, k0); };
      auto stQp = [&](int mt, int nt, f32x4 a) {
        int r0 = mt * 16 + kgrp * 4;
        int c = nt * 16 + mrow;
#pragma unroll
        for (int j = 0; j < 4; ++j) *(short*)(qb + swzB(r0 + j, c)) = f2bf(a[j]);
      };
      gemm<7, 4, 2, WS>(W_in[2], F_in[2], B_in[2], 64, wid, mrow, kgrp, ldQ, stQp);
      auto ldCat = [&](int r, int k0) {
        int g = r / 14, j = r - g * 14;
        return ldA_st(j < 7 ? sF1 : sF2, g * 7 + (j < 7 ? j : j - 7), k0);
      };
      auto stKV = [&](int mt, int nt, f32x4 a) {
        int r0 = mt * 16 + kgrp * 4;
        if (nt < 4) {
          int c = nt * 16 + mrow;
#pragma unroll
          for (int j = 0; j < 4; ++j) *(short*)(kbp + swzB(r0 + j, c)) = f2bf(a[j]);
        } else {
          int d = (nt - 4) * 16 + mrow;
#pragma unroll
          for (int j = 0; j < 4; ++j) {
            int r = r0 + j;
            int gg = r / 14;
            int col = gg * 16 + (r - gg * 14);
            *(short*)(vt + d * 512 + ((((col >> 3) ^ (d & 7)) << 4) | ((col & 7) << 1))) = f2bf(a[j]);
          }
        }
      };
      gemm<14, 8, 2, WS>(W_in[2] + 64 * 64, F_in[2] + 64 * 64, B_in[2] + 64, 64,
                         wid, mrow, kgrp, ldCat, stKV);
      __syncthreads();
      attn_phase<true>(qb, kbp, vt, pbw, wid, mrow, kgrp);
      __syncthreads();
      auto ldCtx = [&](int r, int k0) { return ldA_bf(qb, r, k0); };
      auto stRes = [&](int mt, int nt, f32x4 a) {
        int r0 = mt * 16 + kgrp * 4;
        int c = nt * 16 + mrow;
#pragma unroll
        for (int j = 0; j < 4; ++j) {
          float* p = (float*)(sQ + swzS(r0 + j, c));
          *p += a[j];
        }
      };
      gemm<7, 4, 2, WS>(W_out[2], F_out[2], B_out[2], 64, wid, mrow, kgrp, ldCtx, stRes);
      __syncthreads();
    }

    // ---------- FFN ----------
    {
      auto ldQ = [&](int r, int k0) { return ldA_st(sQ, r, k0); };
      auto stH = [&](int mt, int nt, f32x4 a) {
        int r0 = mt * 16 + kgrp * 4;
        int c = nt * 16 + mrow;
#pragma unroll
        for (int j = 0; j < 4; ++j)
          *(short*)(qb + swzB(r0 + j, c)) = f2bf(fmaxf(a[j], 0.f));
      };
      gemm<7, 2, 2, WS>(W_f1, F_f1, B_f1, 64, wid, mrow, kgrp, ldQ, stH);
      __syncthreads();
      auto ldH = [&](int r, int k0) { return ldA_bf(qb, r, k0); };
      auto stRes = [&](int mt, int nt, f32x4 a) {
        int r0 = mt * 16 + kgrp * 4;
        int c = nt * 16 + mrow;
#pragma unroll
        for (int j = 0; j < 4; ++j) {
          float* p = (float*)(sQ + swzS(r0 + j, c));
          *p += a[j];
        }
      };
      gemm<7, 4, 1, WS>(W_f2, F_f2, B_f2, 32, wid, mrow, kgrp, ldH, stRes);
      __syncthreads();
    }
  }

  // ---------- pose head ----------
  float* cs = (float*)(smem + OFF_KB);   // alias kb (free now): [16][64] fp32
  for (int item = t; item < G * E; item += NTHREADS) {
    int g = item >> 6, c = item & 63;
    float a = 0.f;
#pragma unroll
    for (int s = 0; s < 7; ++s) a += *(const float*)(sQ + swzS(g * 7 + s, c));
    cs[item] = a;
  }
  __syncthreads();
  const int ncols = bi ? 3 : 4;
  if (t < G * ncols) {
    int g = t / ncols, cc = t - g * ncols;
    const float* wv = bi ? (fc_trans_w + cc * 64) : (fc_rot_w + cc * 64);
    float acc = 0.f;
#pragma unroll
    for (int k = 0; k < 64; ++k) acc += cs[g * 64 + k] * wv[k];
    float bb = bi ? fc_trans_b[cc] : fc_rot_b[cc];
    out[(size_t)(b0 + g) * 7 + (bi ? 4 : 0) + cc] = acc * (1.f / 7.f) + bb;
  }
}

// Convert all weight matrices fp32 -> bf16 into workspace (once per call).
__global__ void prep_kernel(const float* __restrict__ a0, const float* __restrict__ a1,
                            const float* __restrict__ a2, const float* __restrict__ a3,
                            const float* __restrict__ a4, const float* __restrict__ a5,
                            const float* __restrict__ a6, const float* __restrict__ a7,
                            short* __restrict__ dst)
{
  for (int i = blockIdx.x * blockDim.x + threadIdx.x; i < 958464;
       i += gridDim.x * blockDim.x) {
    const float* s; int j;
    if      (i < 221184) { s = a0; j = i; }
    else if (i < 442368) { s = a1; j = i - 221184; }
    else if (i < 663552) { s = a2; j = i - 442368; }
    else if (i < 737280) { s = a3; j = i - 663552; }
    else if (i < 811008) { s = a4; j = i - 737280; }
    else if (i < 884736) { s = a5; j = i - 811008; }
    else if (i < 921600) { s = a6; j = i - 884736; }
    else                 { s = a7; j = i - 921600; }
    dst[i] = f2bf(s[j]);
  }
}

} // namespace

extern "C" void kernel_launch(void* const* d_in, const int* in_sizes, int n_in,
                              void* d_out, int out_size, void* d_ws, size_t ws_size,
                              hipStream_t stream)
{
  const float* feature1    = (const float*)d_in[0];
  const float* feature2    = (const float*)d_in[1];
  const float* sa1_win     = (const float*)d_in[2];
  const float* sa1_bin     = (const float*)d_in[3];
  const float* sa1_wout    = (const float*)d_in[4];
  const float* sa1_bout    = (const float*)d_in[5];
  const float* sa2_win     = (const float*)d_in[6];
  const float* sa2_bin     = (const float*)d_in[7];
  const float* sa2_wout    = (const float*)d_in[8];
  const float* sa2_bout    = (const float*)d_in[9];
  const float* ca_win      = (const float*)d_in[10];
  const float* ca_bin      = (const float*)d_in[11];
  const float* ca_wout     = (const float*)d_in[12];
  const float* ca_bout     = (const float*)d_in[13];
  const float* ff_w1       = (const float*)d_in[14];
  const float* ff_b1       = (const float*)d_in[15];
  const float* ff_w2       = (const float*)d_in[16];
  const float* ff_b2       = (const float*)d_in[17];
  const float* query_embed = (const float*)d_in[18];
  const float* fc_rot_w    = (const float*)d_in[19];
  const float* fc_rot_b    = (const float*)d_in[20];
  const float* fc_trans_w  = (const float*)d_in[21];
  const float* fc_trans_b  = (const float*)d_in[22];

  const bool ws_ok = (d_ws != nullptr) && (ws_size >= (size_t)958464 * 2);
  dim3 grid(BB / G, 2);

  if (ws_ok) {
    prep_kernel<<<dim3(936), 512, 0, stream>>>(sa1_win, sa2_win, ca_win,
                                               sa1_wout, sa2_wout, ca_wout,
                                               ff_w1, ff_w2, (short*)d_ws);
    hipFuncSetAttribute(reinterpret_cast<const void*>(&pose_kernel<true>),
                        hipFuncAttributeMaxDynamicSharedMemorySize, SMEM_TOTAL);
    pose_kernel<true><<<grid, NTHREADS, SMEM_TOTAL, stream>>>(
        feature1, feature2,
        sa1_win, sa1_bin, sa1_wout, sa1_bout,
        sa2_win, sa2_bin, sa2_wout, sa2_bout,
        ca_win, ca_bin, ca_wout, ca_bout,
        ff_w1, ff_b1, ff_w2, ff_b2,
        query_embed, fc_rot_w, fc_rot_b, fc_trans_w, fc_trans_b,
        (const short*)d_ws, (float*)d_out);
  } else {
    hipFuncSetAttribute(reinterpret_cast<const void*>(&pose_kernel<false>),
                        hipFuncAttributeMaxDynamicSharedMemorySize, SMEM_TOTAL);
    pose_kernel<false><<<grid, NTHREADS, SMEM_TOTAL, stream>>>(
        feature1, feature2,
        sa1_win, sa1_bin, sa1_wout, sa1_bout,
        sa2_win, sa2_bin, sa2_wout, sa2_bout,
        ca_win, ca_bin, ca_wout, ca_bout,
        ff_w1, ff_b1, ff_w2, ff_b2,
        query_embed, fc_rot_w, fc_rot_b, fc_trans_w, fc_trans_b,
        (const short*)d_ws, (float*)d_out);
  }
}

// Round 3
// 1300.677 us; speedup vs baseline: 14.9373x; 2.2550x over previous
//
#include <hip/hip_runtime.h>
#include <hip/hip_bf16.h>

namespace {

using bf16x8 = __attribute__((ext_vector_type(8))) short;
using f32x4  = __attribute__((ext_vector_type(4))) float;

constexpr int NL = 9, S = 7, BB = 8192;
constexpr int G = 8;            // sequences per block
constexpr int M = G * S;        // 56 token rows
constexpr int NT = 512;

// LDS layout (bytes)
constexpr int OFF_F1 = 0;       // fp32 [56][64] swizzled (32B granule)
constexpr int OFF_F2 = 14336;
constexpr int OFF_Q  = 28672;
constexpr int OFF_QB = 43008;   // bf16 [56][64] swizzled (16B granule): q/ctx/ffn-hidden
constexpr int OFF_KB = 50176;   // bf16 [112][64] swizzled
constexpr int OFF_VT = 64512;   // bf16 V [64 d][128 kv] swizzled (16B granule)
constexpr int SMEM_TOTAL = 80896;   // <= 81920 -> 2 blocks/CU

__device__ __forceinline__ unsigned short f2bf(float f) {
  union { __hip_bfloat16 h; unsigned short s; } u;
  u.h = __float2bfloat16(f);
  return u.s;
}
__device__ __forceinline__ uint32_t pk2(float a, float b) {
  return (uint32_t)f2bf(a) | ((uint32_t)f2bf(b) << 16);
}
__device__ __forceinline__ int swzS(int r, int c) {   // fp32 [*][64]
  return r * 256 + ((((c >> 3) ^ (r & 7)) << 5) | ((c & 7) << 2));
}
__device__ __forceinline__ int swzB(int r, int c) {   // bf16 [*][64]
  return r * 128 + ((((c >> 3) ^ (r & 7)) << 4) | ((c & 7) << 1));
}
__device__ __forceinline__ int swzV(int d, int kv) {  // bf16 [64][128]
  return d * 256 + ((((kv >> 3) ^ (d & 7)) << 4) | ((kv & 7) << 1));
}
__device__ __forceinline__ int div7(int t) { return (t * 9363) >> 16; }  // t < 56

// state fp32 (swizzled) -> bf16x8 fragment: 8 consecutive k (k0 % 8 == 0)
__device__ __forceinline__ bf16x8 ldStateFrag(const char* base, int r, int k0) {
  const float4* p = (const float4*)(base + r * 256 + (((k0 >> 3) ^ (r & 7)) << 5));
  float4 x = p[0], y = p[1];
  union { bf16x8 v; uint32_t u[4]; } o;
  o.u[0] = pk2(x.x, x.y); o.u[1] = pk2(x.z, x.w);
  o.u[2] = pk2(y.x, y.y); o.u[3] = pk2(y.z, y.w);
  return o.v;
}
__device__ __forceinline__ bf16x8 ldBfFrag(const char* base, int r, int k0) {
  return *(const bf16x8*)(base + r * 128 + (((k0 >> 3) ^ (r & 7)) << 4));
}

// Swapped-operand GEMM over a 64(or 32)-K projection.
// Normal tiles (nt < VNT):   D = W x state^T  -> lane: token=q col, 4 consecutive
//   features rows -> packed 8B stores; bias loaded as float4 into acc.
// V tiles (nt >= VNT):       D = state x W^T  -> lane: feature=q col, 4 tokens.
template <int MTOT, int NTOT, int KF, int WMG, int WNG, int VNT, bool WS,
          class BLD, class STN, class STV>
__device__ __forceinline__ void gemm_sw(const short* __restrict__ wbf,
                                        const float* __restrict__ wf,
                                        const float* __restrict__ bias,
                                        int ldK, int wid, int lane,
                                        BLD bld, STN stn, STV stv)
{
  const int wm = wid / WNG, wn = wid % WNG;
  const int q = lane & 15, gI = lane >> 4;
  constexpr int MPW = (MTOT + WMG - 1) / WMG;
  constexpr int NPW = NTOT / WNG;
  bf16x8 bfr[MPW][KF];
#pragma unroll
  for (int i = 0; i < MPW; ++i) {
    const int mt = wm * MPW + i;
    if (mt < MTOT) {
#pragma unroll
      for (int kf = 0; kf < KF; ++kf)
        bfr[i][kf] = bld(mt * 16 + q, kf * 32 + gI * 8);
    }
  }
#pragma unroll
  for (int j = 0; j < NPW; ++j) {
    const int nt = wn * NPW + j;
    bf16x8 afr[KF];
#pragma unroll
    for (int kf = 0; kf < KF; ++kf) {
      const int k0 = kf * 32 + gI * 8;
      if constexpr (WS) {
        afr[kf] = *(const bf16x8*)(wbf + (size_t)(nt * 16 + q) * ldK + k0);
      } else {
        const float* wp = wf + (size_t)(nt * 16 + q) * ldK + k0;
        float4 x = *(const float4*)wp, y = *(const float4*)(wp + 4);
        union { bf16x8 v; uint32_t u[4]; } o;
        o.u[0] = pk2(x.x, x.y); o.u[1] = pk2(x.z, x.w);
        o.u[2] = pk2(y.x, y.y); o.u[3] = pk2(y.z, y.w);
        afr[kf] = o.v;
      }
    }
    if (nt < VNT) {
      const float4 b4 = *(const float4*)(bias + nt * 16 + gI * 4);
#pragma unroll
      for (int i = 0; i < MPW; ++i) {
        const int mt = wm * MPW + i;
        if (mt < MTOT) {
          f32x4 acc = { b4.x, b4.y, b4.z, b4.w };
#pragma unroll
          for (int kf = 0; kf < KF; ++kf)
            acc = __builtin_amdgcn_mfma_f32_16x16x32_bf16(afr[kf], bfr[i][kf], acc, 0, 0, 0);
          stn(mt, nt, acc);
        }
      }
    } else {
      const float bv = bias[nt * 16 + q];
#pragma unroll
      for (int i = 0; i < MPW; ++i) {
        const int mt = wm * MPW + i;
        if (mt < MTOT) {
          f32x4 acc = { bv, bv, bv, bv };
#pragma unroll
          for (int kf = 0; kf < KF; ++kf)
            acc = __builtin_amdgcn_mfma_f32_16x16x32_bf16(bfr[i][kf], afr[kf], acc, 0, 0, 0);
          stv(mt, nt, acc);
        }
      }
    }
  }
}

// Attention: wave wid owns sequence g = wid, loops over 4 heads.
// S^T = K x Q^T (lane: col q, rows kv = gI*4+j) -> in-lane softmax ->
// packed P is directly the PV B-fragment; PV A-frag = 8B read of V[d][kv].
template <bool CA_>
__device__ __forceinline__ void attn(char* qb, const char* kb, const char* vt,
                                     int wid, int lane)
{
  const int q = lane & 15, gI = lane >> 4;
  const int g = wid;
  constexpr int KVL = CA_ ? 14 : 7;
#pragma unroll
  for (int h = 0; h < 4; ++h) {
    bf16x8 kfrag = {}, qfrag = {};
    if (gI < 2) {
      int qrow = g * 7 + q; qrow = qrow > 55 ? 55 : qrow;
      qfrag = ldBfFrag(qb, qrow, h * 16 + gI * 8);
      int kvr;
      if constexpr (CA_) {
        kvr = (q < 7) ? (g * 7 + q) : (49 + g * 7 + q);
        kvr = kvr > 111 ? 111 : kvr;
      } else {
        kvr = g * 7 + q; kvr = kvr > 55 ? 55 : kvr;
      }
      kfrag = ldBfFrag(kb, kvr, h * 16 + gI * 8);
    }
    f32x4 s = { 0.f, 0.f, 0.f, 0.f };
    s = __builtin_amdgcn_mfma_f32_16x16x32_bf16(kfrag, qfrag, s, 0, 0, 0);

    float e[4]; float sum = 0.f;
#pragma unroll
    for (int jj = 0; jj < 4; ++jj) {
      const int kvloc = gI * 4 + jj;
      const float tt = fminf(s[jj] * 0.36067376f, 60.f);   // *0.25 * log2(e)
      e[jj] = (kvloc < KVL) ? exp2f(tt) : 0.f;
      sum += e[jj];
    }
    sum += __shfl_xor(sum, 16);
    sum += __shfl_xor(sum, 32);
    const float inv = __builtin_amdgcn_rcpf(sum);

    union { bf16x8 v; uint32_t u[4]; } pb;
    pb.u[0] = pk2(e[0] * inv, e[1] * inv);
    pb.u[1] = pk2(e[2] * inv, e[3] * inv);
    pb.u[2] = 0; pb.u[3] = 0;

    const int d = h * 16 + q;
    const int kv0 = (CA_ ? g * 16 : g * 8) + gI * 4;
    const uint2 vv = *(const uint2*)(vt + swzV(d, kv0));
    union { bf16x8 v; uint32_t u[4]; } va;
    va.u[0] = vv.x; va.u[1] = vv.y; va.u[2] = 0; va.u[3] = 0;

    f32x4 o = { 0.f, 0.f, 0.f, 0.f };
    o = __builtin_amdgcn_mfma_f32_16x16x32_bf16(va.v, pb.v, o, 0, 0, 0);

    if (q < 7) {
      const int tok = g * 7 + q, c0 = h * 16 + gI * 4;
      *(uint2*)(qb + swzB(tok, c0)) = make_uint2(pk2(o[0], o[1]), pk2(o[2], o[3]));
    }
  }
}

template <bool WS>
__global__ __launch_bounds__(NT, 4) void pose_kernel(
    const float* __restrict__ feature1, const float* __restrict__ feature2,
    const float* __restrict__ sa1_win, const float* __restrict__ sa1_bin,
    const float* __restrict__ sa1_wout, const float* __restrict__ sa1_bout,
    const float* __restrict__ sa2_win, const float* __restrict__ sa2_bin,
    const float* __restrict__ sa2_wout, const float* __restrict__ sa2_bout,
    const float* __restrict__ ca_win, const float* __restrict__ ca_bin,
    const float* __restrict__ ca_wout, const float* __restrict__ ca_bout,
    const float* __restrict__ ff_w1, const float* __restrict__ ff_b1,
    const float* __restrict__ ff_w2, const float* __restrict__ ff_b2,
    const float* __restrict__ query_embed,
    const float* __restrict__ fc_rot_w, const float* __restrict__ fc_rot_b,
    const float* __restrict__ fc_trans_w, const float* __restrict__ fc_trans_b,
    const short* __restrict__ wbf, float* __restrict__ out)
{
  extern __shared__ char smem[];
  char* sF1 = smem + OFF_F1;
  char* sF2 = smem + OFF_F2;
  char* sQ  = smem + OFF_Q;
  char* qb  = smem + OFF_QB;
  char* kb  = smem + OFF_KB;
  char* vt  = smem + OFF_VT;

  const int t = threadIdx.x;
  const int wid = t >> 6, lane = t & 63;
  const int q = lane & 15, gI = lane >> 4;
  const int bi = blockIdx.y;
  const int b0 = blockIdx.x * G;

  // zero-init V buffer once (pad slots must be finite: NaN*0 = NaN in MFMA)
  {
    const uint4 z = { 0, 0, 0, 0 };
    for (int i = t; i < 1024; i += NT) ((uint4*)vt)[i] = z;
  }
  // load per-sequence state (coalesced) into swizzled fp32 tiles
  {
    const float* f1p = feature1 + (size_t)b0 * (S * 64);
    const float* f2p = feature2 + (size_t)b0 * (S * 64);
    const float* qe  = query_embed + (size_t)bi * (S * 64);
    for (int idx = t; idx < M * 64; idx += NT) {
      const int r = idx >> 6, c = idx & 63;
      const int s = r - div7(r) * 7;
      *(float*)(sF1 + swzS(r, c)) = f1p[idx];
      *(float*)(sF2 + swzS(r, c)) = f2p[idx];
      *(float*)(sQ + swzS(r, c))  = qe[s * 64 + c];
    }
  }
  __syncthreads();

  const auto stv_none = [](int, int, f32x4) {};

  for (int li = 0; li < NL; ++li) {
    const int wo = bi * NL + li;
    const short* W_in[3]  = { wbf + 0      + wo * 12288,
                              wbf + 221184 + wo * 12288,
                              wbf + 442368 + wo * 12288 };
    const short* W_out[3] = { wbf + 663552 + wo * 4096,
                              wbf + 737280 + wo * 4096,
                              wbf + 811008 + wo * 4096 };
    const short* W_f1 = wbf + 884736 + wo * 2048;
    const short* W_f2 = wbf + 921600 + wo * 2048;
    const float* F_in[3]  = { sa1_win + wo * 12288, sa2_win + wo * 12288, ca_win + wo * 12288 };
    const float* F_out[3] = { sa1_wout + wo * 4096, sa2_wout + wo * 4096, ca_wout + wo * 4096 };
    const float* B_in[3]  = { sa1_bin + wo * 192, sa2_bin + wo * 192, ca_bin + wo * 192 };
    const float* B_out[3] = { sa1_bout + wo * 64, sa2_bout + wo * 64, ca_bout + wo * 64 };

    // ---------- self-attention on f1, then f2 ----------
    for (int sa = 0; sa < 2; ++sa) {
      char* ST = sa ? sF2 : sF1;
      auto bld = [&](int r, int k0) { return ldStateFrag(ST, r > 55 ? 55 : r, k0); };
      auto stn = [&](int mt, int nt, f32x4 a) {        // nt<4: Q, 4..7: K
        const int tok = mt * 16 + q; if (tok >= M) return;
        if (nt < 4) {
          *(uint2*)(qb + swzB(tok, nt * 16 + gI * 4)) =
              make_uint2(pk2(a[0], a[1]), pk2(a[2], a[3]));
        } else {
          *(uint2*)(kb + swzB(tok, (nt - 4) * 16 + gI * 4)) =
              make_uint2(pk2(a[0], a[1]), pk2(a[2], a[3]));
        }
      };
      auto stv = [&](int mt, int nt, f32x4 a) {        // nt>=8: V -> vt[d][kv]
        const int d = (nt - 8) * 16 + q;
#pragma unroll
        for (int jj = 0; jj < 4; ++jj) {
          const int tok = mt * 16 + gI * 4 + jj;
          if (tok < M) {
            const int g = div7(tok);
            *(short*)(vt + swzV(d, g * 8 + (tok - g * 7))) = (short)f2bf(a[jj]);
          }
        }
      };
      gemm_sw<4, 12, 2, 2, 4, 8, WS>(W_in[sa], F_in[sa], B_in[sa], 64, wid, lane, bld, stn, stv);
      __syncthreads();
      attn<false>(qb, kb, vt, wid, lane);
      __syncthreads();
      auto bldc = [&](int r, int k0) { return ldBfFrag(qb, r > 55 ? 55 : r, k0); };
      auto stres = [&](int mt, int nt, f32x4 a) {
        const int tok = mt * 16 + q; if (tok >= M) return;
        const int c0 = nt * 16 + gI * 4;
        float4* p = (float4*)(ST + tok * 256 + (((c0 >> 3) ^ (tok & 7)) << 5) + (c0 & 7) * 4);
        float4 v = *p;
        v.x += a[0]; v.y += a[1]; v.z += a[2]; v.w += a[3];
        *p = v;
      };
      gemm_sw<4, 4, 2, 2, 4, 4, WS>(W_out[sa], F_out[sa], B_out[sa], 64, wid, lane, bldc, stres, stv_none);
      __syncthreads();
    }

    // ---------- cross-attention ----------
    {
      auto bldq = [&](int r, int k0) { return ldStateFrag(sQ, r > 55 ? 55 : r, k0); };
      auto stq = [&](int mt, int nt, f32x4 a) {
        const int tok = mt * 16 + q; if (tok >= M) return;
        *(uint2*)(qb + swzB(tok, nt * 16 + gI * 4)) =
            make_uint2(pk2(a[0], a[1]), pk2(a[2], a[3]));
      };
      gemm_sw<4, 4, 2, 2, 4, 4, WS>(W_in[2], F_in[2], B_in[2], 64, wid, lane, bldq, stq, stv_none);

      for (int src = 0; src < 2; ++src) {
        const char* SRC = src ? sF2 : sF1;
        auto bld = [&](int r, int k0) { return ldStateFrag(SRC, r > 55 ? 55 : r, k0); };
        auto stk = [&](int mt, int nt, f32x4 a) {      // nt<4: K
          const int tok = mt * 16 + q; if (tok >= M) return;
          *(uint2*)(kb + swzB(tok + src * 56, nt * 16 + gI * 4)) =
              make_uint2(pk2(a[0], a[1]), pk2(a[2], a[3]));
        };
        auto stv = [&](int mt, int nt, f32x4 a) {      // nt>=4: V
          const int d = (nt - 4) * 16 + q;
#pragma unroll
          for (int jj = 0; jj < 4; ++jj) {
            const int tok = mt * 16 + gI * 4 + jj;
            if (tok < M) {
              const int g = div7(tok);
              *(short*)(vt + swzV(d, g * 16 + (tok - g * 7) + src * 7)) = (short)f2bf(a[jj]);
            }
          }
        };
        gemm_sw<4, 8, 2, 2, 4, 4, WS>(W_in[2] + 4096, F_in[2] + 4096, B_in[2] + 64,
                                      64, wid, lane, bld, stk, stv);
      }
      __syncthreads();
      attn<true>(qb, kb, vt, wid, lane);
      __syncthreads();
      auto bldc = [&](int r, int k0) { return ldBfFrag(qb, r > 55 ? 55 : r, k0); };
      auto stres = [&](int mt, int nt, f32x4 a) {
        const int tok = mt * 16 + q; if (tok >= M) return;
        const int c0 = nt * 16 + gI * 4;
        float4* p = (float4*)(sQ + tok * 256 + (((c0 >> 3) ^ (tok & 7)) << 5) + (c0 & 7) * 4);
        float4 v = *p;
        v.x += a[0]; v.y += a[1]; v.z += a[2]; v.w += a[3];
        *p = v;
      };
      gemm_sw<4, 4, 2, 2, 4, 4, WS>(W_out[2], F_out[2], B_out[2], 64, wid, lane, bldc, stres, stv_none);
      __syncthreads();
    }

    // ---------- FFN ----------
    {
      auto bldq = [&](int r, int k0) { return ldStateFrag(sQ, r > 55 ? 55 : r, k0); };
      auto sth = [&](int mt, int nt, f32x4 a) {        // relu -> qb cols 0..31
        const int tok = mt * 16 + q; if (tok >= M) return;
        *(uint2*)(qb + swzB(tok, nt * 16 + gI * 4)) =
            make_uint2(pk2(fmaxf(a[0], 0.f), fmaxf(a[1], 0.f)),
                       pk2(fmaxf(a[2], 0.f), fmaxf(a[3], 0.f)));
      };
      gemm_sw<4, 2, 2, 4, 2, 2, WS>(W_f1, ff_w1 + wo * 2048, ff_b1 + wo * 32,
                                    64, wid, lane, bldq, sth, stv_none);
      __syncthreads();
      auto bldh = [&](int r, int k0) { return ldBfFrag(qb, r > 55 ? 55 : r, k0); };
      auto stres = [&](int mt, int nt, f32x4 a) {
        const int tok = mt * 16 + q; if (tok >= M) return;
        const int c0 = nt * 16 + gI * 4;
        float4* p = (float4*)(sQ + tok * 256 + (((c0 >> 3) ^ (tok & 7)) << 5) + (c0 & 7) * 4);
        float4 v = *p;
        v.x += a[0]; v.y += a[1]; v.z += a[2]; v.w += a[3];
        *p = v;
      };
      gemm_sw<4, 4, 1, 2, 4, 4, WS>(W_f2, ff_w2 + wo * 2048, ff_b2 + wo * 64,
                                    32, wid, lane, bldh, stres, stv_none);
      __syncthreads();
    }
  }

  // ---------- pose head ----------
  float* cs = (float*)qb;   // [8][64] fp32 scratch (qb is free now)
  {
    const int g = t >> 6, c = t & 63;   // 512 threads == 8*64 items
    float a = 0.f;
#pragma unroll
    for (int s = 0; s < 7; ++s) a += *(const float*)(sQ + swzS(g * 7 + s, c));
    cs[t] = a;
  }
  __syncthreads();
  const int ncols = bi ? 3 : 4;
  if (t < G * ncols) {
    const int g = t / ncols, cc = t - g * ncols;
    const float* wv = bi ? (fc_trans_w + cc * 64) : (fc_rot_w + cc * 64);
    float acc = 0.f;
#pragma unroll
    for (int k = 0; k < 64; ++k) acc += cs[g * 64 + k] * wv[k];
    const float bb = bi ? fc_trans_b[cc] : fc_rot_b[cc];
    out[(size_t)(b0 + g) * 7 + (bi ? 4 : 0) + cc] = acc * (1.f / 7.f) + bb;
  }
}

// Convert all weight matrices fp32 -> bf16 into workspace (once per call).
__global__ void prep_kernel(const float* __restrict__ a0, const float* __restrict__ a1,
                            const float* __restrict__ a2, const float* __restrict__ a3,
                            const float* __restrict__ a4, const float* __restrict__ a5,
                            const float* __restrict__ a6, const float* __restrict__ a7,
                            short* __restrict__ dst)
{
  for (int i = blockIdx.x * blockDim.x + threadIdx.x; i < 958464;
       i += gridDim.x * blockDim.x) {
    const float* s; int j;
    if      (i < 221184) { s = a0; j = i; }
    else if (i < 442368) { s = a1; j = i - 221184; }
    else if (i < 663552) { s = a2; j = i - 442368; }
    else if (i < 737280) { s = a3; j = i - 663552; }
    else if (i < 811008) { s = a4; j = i - 737280; }
    else if (i < 884736) { s = a5; j = i - 811008; }
    else if (i < 921600) { s = a6; j = i - 884736; }
    else                 { s = a7; j = i - 921600; }
    dst[i] = (short)f2bf(s[j]);
  }
}

} // namespace

extern "C" void kernel_launch(void* const* d_in, const int* in_sizes, int n_in,
                              void* d_out, int out_size, void* d_ws, size_t ws_size,
                              hipStream_t stream)
{
  const float* feature1    = (const float*)d_in[0];
  const float* feature2    = (const float*)d_in[1];
  const float* sa1_win     = (const float*)d_in[2];
  const float* sa1_bin     = (const float*)d_in[3];
  const float* sa1_wout    = (const float*)d_in[4];
  const float* sa1_bout    = (const float*)d_in[5];
  const float* sa2_win     = (const float*)d_in[6];
  const float* sa2_bin     = (const float*)d_in[7];
  const float* sa2_wout    = (const float*)d_in[8];
  const float* sa2_bout    = (const float*)d_in[9];
  const float* ca_win      = (const float*)d_in[10];
  const float* ca_bin      = (const float*)d_in[11];
  const float* ca_wout     = (const float*)d_in[12];
  const float* ca_bout     = (const float*)d_in[13];
  const float* ff_w1       = (const float*)d_in[14];
  const float* ff_b1       = (const float*)d_in[15];
  const float* ff_w2       = (const float*)d_in[16];
  const float* ff_b2       = (const float*)d_in[17];
  const float* query_embed = (const float*)d_in[18];
  const float* fc_rot_w    = (const float*)d_in[19];
  const float* fc_rot_b    = (const float*)d_in[20];
  const float* fc_trans_w  = (const float*)d_in[21];
  const float* fc_trans_b  = (const float*)d_in[22];

  const bool ws_ok = (d_ws != nullptr) && (ws_size >= (size_t)958464 * 2);
  dim3 grid(BB / G, 2);

  if (ws_ok) {
    prep_kernel<<<dim3(936), 512, 0, stream>>>(sa1_win, sa2_win, ca_win,
                                               sa1_wout, sa2_wout, ca_wout,
                                               ff_w1, ff_w2, (short*)d_ws);
    hipFuncSetAttribute(reinterpret_cast<const void*>(&pose_kernel<true>),
                        hipFuncAttributeMaxDynamicSharedMemorySize, SMEM_TOTAL);
    pose_kernel<true><<<grid, NT, SMEM_TOTAL, stream>>>(
        feature1, feature2,
        sa1_win, sa1_bin, sa1_wout, sa1_bout,
        sa2_win, sa2_bin, sa2_wout, sa2_bout,
        ca_win, ca_bin, ca_wout, ca_bout,
        ff_w1, ff_b1, ff_w2, ff_b2,
        query_embed, fc_rot_w, fc_rot_b, fc_trans_w, fc_trans_b,
        (const short*)d_ws, (float*)d_out);
  } else {
    hipFuncSetAttribute(reinterpret_cast<const void*>(&pose_kernel<false>),
                        hipFuncAttributeMaxDynamicSharedMemorySize, SMEM_TOTAL);
    pose_kernel<false><<<grid, NT, SMEM_TOTAL, stream>>>(
        feature1, feature2,
        sa1_win, sa1_bin, sa1_wout, sa1_bout,
        sa2_win, sa2_bin, sa2_wout, sa2_bout,
        ca_win, ca_bin, ca_wout, ca_bout,
        ff_w1, ff_b1, ff_w2, ff_b2,
        query_embed, fc_rot_w, fc_rot_b, fc_trans_w, fc_trans_b,
        (const short*)d_ws, (float*)d_out);
  }
}